// Round 1
// baseline (1287.610 us; speedup 1.0000x reference)
//
#include <hip/hip_runtime.h>
#include <cstdint>

#define NN 2000
#define BB 4
#define SEQ 30
#define NODES (BB*NN)            // 8000
#define EPB 128000               // edges per single-graph
#define NEDGE (BB*EPB + NODES)   // 520000

// ---------------- workspace layout (float offsets) ----------------
constexpr size_t WP0 = 96 * 256;    // layer0 permuted weights (din32+hid64 rows x 256 gates)
constexpr size_t WP1 = 192 * 256;   // layer1 (din128+hid64 rows x 256)
constexpr size_t OFF_WP0F = 0;
constexpr size_t OFF_WP0B = OFF_WP0F + WP0;
constexpr size_t OFF_WP1F = OFF_WP0B + WP0;
constexpr size_t OFF_WP1B = OFF_WP1F + WP1;
constexpr size_t OFF_BP0F = OFF_WP1B + WP1;
constexpr size_t OFF_BP0B = OFF_BP0F + 256;
constexpr size_t OFF_BP1F = OFF_BP0B + 256;
constexpr size_t OFF_BP1B = OFF_BP1F + 256;
constexpr size_t OFF_H0   = OFF_BP1B + 256;                       // 8000*30*128
constexpr size_t OFF_LAST = OFF_H0 + (size_t)NODES * SEQ * 128;   // 8000*128
constexpr size_t OFF_XP   = OFF_LAST + (size_t)NODES * 128;       // 8000*256
constexpr size_t OFF_AS   = OFF_XP + (size_t)NODES * 256;         // 8000*4
constexpr size_t OFF_AD   = OFF_AS + (size_t)NODES * 4;
constexpr size_t OFF_F1   = OFF_AD + (size_t)NODES * 4;           // 8000*64
constexpr size_t OFF_F2   = OFF_F1 + (size_t)NODES * 64;
constexpr size_t OFF_INT  = OFF_F2 + (size_t)NODES * 64;          // int region below
constexpr size_t IOFF_CNT  = 0;
constexpr size_t IOFF_OFFS = 8192;
constexpr size_t IOFF_CUR  = 16384;
constexpr size_t IOFF_SSRC = 24576;

// ---------------- device helpers ----------------
__device__ __forceinline__ float rdlane(float v, int k) {
  return __uint_as_float((unsigned)__builtin_amdgcn_readlane((int)__float_as_uint(v), k));
}
__device__ __forceinline__ float sigf(float x) { return 1.f / (1.f + __expf(-x)); }
__device__ __forceinline__ float tanhfast(float x) { return 1.f - 2.f / (__expf(2.f * x) + 1.f); }
__device__ __forceinline__ void fma4(float4& a, float s, const float4& w) {
  a.x = fmaf(s, w.x, a.x); a.y = fmaf(s, w.y, a.y);
  a.z = fmaf(s, w.z, a.z); a.w = fmaf(s, w.w, a.w);
}

// ---------------- weight permutation ----------------
// wp[k][c], c = 4*j + q  holds W[g][k] with g = q*64 + j.
// Lane j then reads a float4 = (i,f,g,o)-weights of hidden unit j for row k.
__global__ void permute_w(const float* __restrict__ Wih, const float* __restrict__ Whh,
                          const float* __restrict__ bias, float* __restrict__ wp,
                          float* __restrict__ bp, int DIN) {
  const int k = blockIdx.x;
  const int c = threadIdx.x;
  const int jj = c >> 2, q = c & 3;
  const int g = q * 64 + jj;
  const float v = (k < DIN) ? Wih[g * DIN + k] : Whh[g * 64 + (k - DIN)];
  wp[k * 256 + c] = v;
  if (k == 0) bp[c] = bias[g];
}

// ---------------- LSTM scan ----------------
// One wave handles M=8 sequences, all 256 gates (lane j owns unit j: gates j,64+j,128+j,192+j).
// h/c state and inputs live in registers; activations broadcast via v_readlane;
// W_hh (64KB) staged in LDS; input-projection weights stream from L2.
// WRITE_ALL=true (layer0): write h every step into h0[n][s][dirOff+j].
// WRITE_ALL=false (layer1): dir0 = full forward scan -> last[n][0:64];
//                           dir1 = single step at s=29 (reverse-scan first step) -> last[n][64:128].
template<int DIN, bool WRITE_ALL>
__global__ __launch_bounds__(256)
void lstm_scan(const float* __restrict__ xin,
               const float* __restrict__ wpF, const float* __restrict__ wpB,
               const float* __restrict__ bpF, const float* __restrict__ bpB,
               float* __restrict__ hout) {
  constexpr int M = 8;
  __shared__ float whh[64 * 256];   // exactly 64 KB
  const int dir = blockIdx.y;
  const float* __restrict__ wp = dir ? wpB : wpF;
  const float* __restrict__ bp = dir ? bpB : bpF;
  {
    const float4* src = (const float4*)(wp + DIN * 256);
    float4* dst = (float4*)whh;
    for (int idx = threadIdx.x; idx < 64 * 256 / 4; idx += 256) dst[idx] = src[idx];
  }
  __syncthreads();

  const int wv = threadIdx.x >> 6;
  const int j  = threadIdx.x & 63;
  const int n0 = (blockIdx.x * 4 + wv) * M;
  const int dirOff = dir * 64;
  const float4 bias4 = *(const float4*)(bp + 4 * j);

  float hreg[M], creg[M];
#pragma unroll
  for (int m = 0; m < M; ++m) { hreg[m] = 0.f; creg[m] = 0.f; }

  int xbase[M];
#pragma unroll
  for (int m = 0; m < M; ++m) {
    const int n = n0 + m;
    if (DIN == 32) {
      const int b = n / NN, node = n - b * NN;
      xbase[m] = (b * SEQ * NN + node) * 32 + (j & 31);
    } else {
      xbase[m] = n * SEQ * 128 + j;
    }
  }

  int steps = SEQ;
  const bool rev = (dir != 0);
  if (!WRITE_ALL && dir) steps = 1;

  for (int t = 0; t < steps; ++t) {
    const int s = rev ? (SEQ - 1 - t) : t;

    float xr0[M], xr1[M];
#pragma unroll
    for (int m = 0; m < M; ++m) {
      if (DIN == 32) {
        xr0[m] = xin[xbase[m] + s * (NN * 32)];
        xr1[m] = 0.f;
      } else {
        xr0[m] = xin[xbase[m] + s * 128];
        xr1[m] = xin[xbase[m] + s * 128 + 64];
      }
    }

    float4 acc[M];
#pragma unroll
    for (int m = 0; m < M; ++m) acc[m] = bias4;

    // ---- input projection (weights from global/L2) ----
    if (DIN == 32) {
#pragma unroll 8
      for (int k = 0; k < 32; ++k) {
        const float4 w4 = *(const float4*)(wp + k * 256 + 4 * j);
#pragma unroll
        for (int m = 0; m < M; ++m) fma4(acc[m], rdlane(xr0[m], k), w4);
      }
    } else {
#pragma unroll 8
      for (int k = 0; k < 64; ++k) {
        const float4 w4 = *(const float4*)(wp + k * 256 + 4 * j);
#pragma unroll
        for (int m = 0; m < M; ++m) fma4(acc[m], rdlane(xr0[m], k), w4);
      }
#pragma unroll 8
      for (int k = 0; k < 64; ++k) {
        const float4 w4 = *(const float4*)(wp + (64 + k) * 256 + 4 * j);
#pragma unroll
        for (int m = 0; m < M; ++m) fma4(acc[m], rdlane(xr1[m], k), w4);
      }
    }

    // ---- recurrent part (W_hh from LDS) ----
#pragma unroll 8
    for (int k = 0; k < 64; ++k) {
      const float4 w4 = *(const float4*)(whh + k * 256 + 4 * j);
#pragma unroll
      for (int m = 0; m < M; ++m) fma4(acc[m], rdlane(hreg[m], k), w4);
    }

    // ---- gate nonlinearities ----
#pragma unroll
    for (int m = 0; m < M; ++m) {
      const float iv = sigf(acc[m].x);
      const float fv = sigf(acc[m].y);
      const float gv = tanhfast(acc[m].z);
      const float ov = sigf(acc[m].w);
      const float c = fv * creg[m] + iv * gv;
      const float h = ov * tanhfast(c);
      creg[m] = c; hreg[m] = h;
      if (WRITE_ALL) hout[((size_t)(n0 + m) * SEQ + s) * 128 + dirOff + j] = h;
    }
  }
  if (!WRITE_ALL) {
#pragma unroll
    for (int m = 0; m < M; ++m) hout[(size_t)(n0 + m) * 128 + dirOff + j] = hreg[m];
  }
}

// ---------------- CSR build (once; shared by both GAT layers) ----------------
__global__ void csr_zero(int* cnt) {
  const int i = blockIdx.x * 256 + threadIdx.x;
  if (i < NODES + 1) cnt[i] = 0;
}
__global__ void csr_count(const int* __restrict__ ei, int* __restrict__ cnt) {
  const int e = blockIdx.x * 256 + threadIdx.x;
  if (e >= NEDGE) return;
  int dst;
  if (e < BB * EPB) { const int b = e / EPB, i = e - b * EPB; dst = ei[EPB + i] + b * NN; }
  else dst = e - BB * EPB;
  atomicAdd(&cnt[dst], 1);
}
__global__ void csr_scan(const int* __restrict__ cnt, int* __restrict__ offs, int* __restrict__ cur) {
  __shared__ int sums[1024];
  const int t = threadIdx.x;
  const int base = t * 8;
  int loc[8]; int s = 0;
#pragma unroll
  for (int i = 0; i < 8; ++i) {
    const int v = (base + i < NODES) ? cnt[base + i] : 0;
    loc[i] = s; s += v;
  }
  sums[t] = s; __syncthreads();
  for (int off = 1; off < 1024; off <<= 1) {
    int v = 0;
    if (t >= off) v = sums[t - off];
    __syncthreads();
    sums[t] += v;
    __syncthreads();
  }
  const int pre = (t == 0) ? 0 : sums[t - 1];
#pragma unroll
  for (int i = 0; i < 8; ++i) {
    if (base + i < NODES) { const int o = pre + loc[i]; offs[base + i] = o; cur[base + i] = o; }
  }
  if (t == 1023) offs[NODES] = sums[1023];
}
__global__ void csr_fill(const int* __restrict__ ei, int* __restrict__ cur, int* __restrict__ ssrc) {
  const int e = blockIdx.x * 256 + threadIdx.x;
  if (e >= NEDGE) return;
  int src, dst;
  if (e < BB * EPB) {
    const int b = e / EPB, i = e - b * EPB;
    src = ei[i] + b * NN; dst = ei[EPB + i] + b * NN;
  } else { src = dst = e - BB * EPB; }
  const int pos = atomicAdd(&cur[dst], 1);
  ssrc[pos] = src;
}

// ---------------- GAT: xp = feat @ gW, plus per-head attention dots ----------------
template<int F>
__global__ __launch_bounds__(256)
void gat_prep(const float* __restrict__ feat, const float* __restrict__ gW,
              const float* __restrict__ asrc, const float* __restrict__ adst,
              float* __restrict__ xp, float* __restrict__ as_, float* __restrict__ ad_) {
  __shared__ float xrow[8 * F];
  const int n0 = blockIdx.x * 8;
  for (int idx = threadIdx.x; idx < 8 * F; idx += 256) xrow[idx] = feat[(size_t)n0 * F + idx];
  __syncthreads();
  const int g = threadIdx.x;           // 0..255 ; head = g>>6 == wave id
  float acc[8];
#pragma unroll
  for (int m = 0; m < 8; ++m) acc[m] = 0.f;
  for (int d = 0; d < F; ++d) {
    const float w = gW[d * 256 + g];
#pragma unroll
    for (int m = 0; m < 8; ++m) acc[m] = fmaf(xrow[m * F + d], w, acc[m]);
  }
#pragma unroll
  for (int m = 0; m < 8; ++m) xp[(size_t)(n0 + m) * 256 + g] = acc[m];
  const float av = asrc[g], dv = adst[g];
  const int h = g >> 6;
#pragma unroll
  for (int m = 0; m < 8; ++m) {
    float s1 = acc[m] * av, s2 = acc[m] * dv;
#pragma unroll
    for (int off = 1; off < 64; off <<= 1) {
      s1 += __shfl_xor(s1, off);
      s2 += __shfl_xor(s2, off);
    }
    if ((g & 63) == 0) {
      as_[(n0 + m) * 4 + h] = s1;
      ad_[(n0 + m) * 4 + h] = s2;
    }
  }
}

// ---------------- GAT: per-destination-node softmax aggregation ----------------
__global__ __launch_bounds__(256)
void gat_agg(const int* __restrict__ offs, const int* __restrict__ ssrc,
             const float* __restrict__ as_, const float* __restrict__ ad_,
             const float* __restrict__ xp, const float* __restrict__ gbias,
             float* __restrict__ outf) {
  const int v = blockIdx.x * 4 + (threadIdx.x >> 6);
  const int lane = threadIdx.x & 63;
  const int beg = offs[v], end = offs[v + 1];
  const float4 adv = *(const float4*)(ad_ + v * 4);

  // pass 1: per-head segment max
  float m0 = -1e30f, m1 = -1e30f, m2 = -1e30f, m3 = -1e30f;
  for (int i = beg + lane; i < end; i += 64) {
    const int sn = ssrc[i];
    const float4 asv = *(const float4*)(as_ + sn * 4);
    float e;
    e = asv.x + adv.x; e = e > 0.f ? e : 0.2f * e; m0 = fmaxf(m0, e);
    e = asv.y + adv.y; e = e > 0.f ? e : 0.2f * e; m1 = fmaxf(m1, e);
    e = asv.z + adv.z; e = e > 0.f ? e : 0.2f * e; m2 = fmaxf(m2, e);
    e = asv.w + adv.w; e = e > 0.f ? e : 0.2f * e; m3 = fmaxf(m3, e);
  }
#pragma unroll
  for (int off = 1; off < 64; off <<= 1) {
    m0 = fmaxf(m0, __shfl_xor(m0, off));
    m1 = fmaxf(m1, __shfl_xor(m1, off));
    m2 = fmaxf(m2, __shfl_xor(m2, off));
    m3 = fmaxf(m3, __shfl_xor(m3, off));
  }

  // pass 2: weighted aggregation (lane = output channel c)
  float a0 = 0, a1 = 0, a2 = 0, a3 = 0, d0 = 0, d1 = 0, d2 = 0, d3 = 0;
  for (int i = beg; i < end; ++i) {
    const int sn = ssrc[i];
    const float4 asv = *(const float4*)(as_ + sn * 4);
    const float* xr = xp + (size_t)sn * 256;
    float e, w;
    e = asv.x + adv.x; e = e > 0.f ? e : 0.2f * e; w = __expf(e - m0); d0 += w; a0 = fmaf(w, xr[lane], a0);
    e = asv.y + adv.y; e = e > 0.f ? e : 0.2f * e; w = __expf(e - m1); d1 += w; a1 = fmaf(w, xr[64 + lane], a1);
    e = asv.z + adv.z; e = e > 0.f ? e : 0.2f * e; w = __expf(e - m2); d2 += w; a2 = fmaf(w, xr[128 + lane], a2);
    e = asv.w + adv.w; e = e > 0.f ? e : 0.2f * e; w = __expf(e - m3); d3 += w; a3 = fmaf(w, xr[192 + lane], a3);
  }
  const float r = 0.25f * (a0 / (d0 + 1e-16f) + a1 / (d1 + 1e-16f) +
                           a2 / (d2 + 1e-16f) + a3 / (d3 + 1e-16f)) + gbias[lane];
  outf[(size_t)v * 64 + lane] = fmaxf(r, 0.f);
}

// ---------------- final: node-mean per batch + 2-layer MLP ----------------
__global__ void final_mlp(const float* __restrict__ feat2,
                          const float* __restrict__ fW1, const float* __restrict__ fb1,
                          const float* __restrict__ fW2, const float* __restrict__ fb2,
                          float* __restrict__ out) {
  const int b = blockIdx.x;
  __shared__ float part[4][64];
  __shared__ float y[64];
  __shared__ float hh[32];
  const int t = threadIdx.x;
  const int c = t & 63, r = t >> 6;
  float s = 0.f;
  for (int i = r; i < NN; i += 4) s += feat2[(size_t)(b * NN + i) * 64 + c];
  part[r][c] = s; __syncthreads();
  if (t < 64) y[t] = (part[0][t] + part[1][t] + part[2][t] + part[3][t]) * (1.0f / NN);
  __syncthreads();
  if (t < 32) {
    float a = fb1[t];
    for (int cc = 0; cc < 64; ++cc) a = fmaf(y[cc], fW1[t * 64 + cc], a);
    hh[t] = fmaxf(a, 0.f);
  }
  __syncthreads();
  if (t == 0) {
    float o = fb2[0];
    for (int jj = 0; jj < 32; ++jj) o = fmaf(hh[jj], fW2[jj], o);
    out[b] = o;
  }
}

// ---------------- launch ----------------
extern "C" void kernel_launch(void* const* d_in, const int* in_sizes, int n_in,
                              void* d_out, int out_size, void* d_ws, size_t ws_size,
                              hipStream_t stream) {
  const float* x_seq = (const float*)d_in[0];
  const int*   ei    = (const int*)d_in[1];
  const float* Wih0f = (const float*)d_in[2];  const float* Whh0f = (const float*)d_in[3];  const float* b0f = (const float*)d_in[4];
  const float* Wih0b = (const float*)d_in[5];  const float* Whh0b = (const float*)d_in[6];  const float* b0b = (const float*)d_in[7];
  const float* Wih1f = (const float*)d_in[8];  const float* Whh1f = (const float*)d_in[9];  const float* b1f = (const float*)d_in[10];
  const float* Wih1b = (const float*)d_in[11]; const float* Whh1b = (const float*)d_in[12]; const float* b1b = (const float*)d_in[13];
  const float* gW0 = (const float*)d_in[14]; const float* gas0 = (const float*)d_in[15];
  const float* gad0 = (const float*)d_in[16]; const float* gb0 = (const float*)d_in[17];
  const float* gW1 = (const float*)d_in[18]; const float* gas1 = (const float*)d_in[19];
  const float* gad1 = (const float*)d_in[20]; const float* gb1 = (const float*)d_in[21];
  const float* fW1 = (const float*)d_in[22]; const float* fb1 = (const float*)d_in[23];
  const float* fW2 = (const float*)d_in[24]; const float* fb2 = (const float*)d_in[25];

  float* ws = (float*)d_ws;
  float* wp0f = ws + OFF_WP0F; float* wp0b = ws + OFF_WP0B;
  float* wp1f = ws + OFF_WP1F; float* wp1b = ws + OFF_WP1B;
  float* bp0f = ws + OFF_BP0F; float* bp0b = ws + OFF_BP0B;
  float* bp1f = ws + OFF_BP1F; float* bp1b = ws + OFF_BP1B;
  float* h0   = ws + OFF_H0;   float* last = ws + OFF_LAST;
  float* xp   = ws + OFF_XP;   float* as_  = ws + OFF_AS;  float* ad_ = ws + OFF_AD;
  float* f1   = ws + OFF_F1;   float* f2   = ws + OFF_F2;
  int* iws  = (int*)(ws + OFF_INT);
  int* cnt  = iws + IOFF_CNT;  int* offs = iws + IOFF_OFFS;
  int* cur  = iws + IOFF_CUR;  int* ssrc = iws + IOFF_SSRC;

  // weight permutation (tiny, once per call)
  permute_w<<<96, 256, 0, stream>>>(Wih0f, Whh0f, b0f, wp0f, bp0f, 32);
  permute_w<<<96, 256, 0, stream>>>(Wih0b, Whh0b, b0b, wp0b, bp0b, 32);
  permute_w<<<192, 256, 0, stream>>>(Wih1f, Whh1f, b1f, wp1f, bp1f, 128);
  permute_w<<<192, 256, 0, stream>>>(Wih1b, Whh1b, b1b, wp1b, bp1b, 128);

  // LSTM layer 0 (both directions, full h0), layer 1 (fwd full scan + bwd 1 step -> last)
  lstm_scan<32, true><<<dim3(250, 2), 256, 0, stream>>>(x_seq, wp0f, wp0b, bp0f, bp0b, h0);
  lstm_scan<128, false><<<dim3(250, 2), 256, 0, stream>>>(h0, wp1f, wp1b, bp1f, bp1b, last);

  // CSR of the (fixed) graph
  csr_zero<<<32, 256, 0, stream>>>(cnt);
  csr_count<<<(NEDGE + 255) / 256, 256, 0, stream>>>(ei, cnt);
  csr_scan<<<1, 1024, 0, stream>>>(cnt, offs, cur);
  csr_fill<<<(NEDGE + 255) / 256, 256, 0, stream>>>(ei, cur, ssrc);

  // GAT layer 0 (input: last, F=128)
  gat_prep<128><<<1000, 256, 0, stream>>>(last, gW0, gas0, gad0, xp, as_, ad_);
  gat_agg<<<2000, 256, 0, stream>>>(offs, ssrc, as_, ad_, xp, gb0, f1);
  // GAT layer 1 (input: f1, F=64)
  gat_prep<64><<<1000, 256, 0, stream>>>(f1, gW1, gas1, gad1, xp, as_, ad_);
  gat_agg<<<2000, 256, 0, stream>>>(offs, ssrc, as_, ad_, xp, gb1, f2);

  // mean over nodes + MLP head
  final_mlp<<<4, 256, 0, stream>>>(f2, fW1, fb1, fW2, fb2, (float*)d_out);
}

// Round 11
// 1102.262 us; speedup vs baseline: 1.1682x; 1.1682x over previous
//
#include <hip/hip_runtime.h>
#include <cstdint>

#define NN 2000
#define BB 4
#define SEQ 30
#define NODES (BB*NN)            // 8000
#define EPB 128000               // edges per single-graph
#define NEDGE (BB*EPB + NODES)   // 520000

// ---------------- workspace layout (4-byte units) ----------------
constexpr size_t U_WPH0F = 0;                                // 48*256 uints
constexpr size_t U_WPH0B = U_WPH0F + 48 * 256;
constexpr size_t U_WPH1F = U_WPH0B + 48 * 256;               // 96*256
constexpr size_t U_WPH1B = U_WPH1F + 96 * 256;
constexpr size_t U_BP0F  = U_WPH1B + 96 * 256;               // 256 floats each
constexpr size_t U_BP0B  = U_BP0F + 256;
constexpr size_t U_BP1F  = U_BP0B + 256;
constexpr size_t U_BP1B  = U_BP1F + 256;
constexpr size_t U_XPK   = U_BP1B + 256;                     // 8000*30*16 uints (packed x)
constexpr size_t U_H0P   = U_XPK + (size_t)NODES * SEQ * 16; // 8000*30*64 uints (packed h0)
constexpr size_t U_LAST  = U_H0P + (size_t)NODES * SEQ * 64; // 8000*128 floats
constexpr size_t U_XP    = U_LAST + (size_t)NODES * 128;     // 8000*256 floats
constexpr size_t U_AS    = U_XP + (size_t)NODES * 256;       // 8000*4
constexpr size_t U_AD    = U_AS + (size_t)NODES * 4;
constexpr size_t U_F1    = U_AD + (size_t)NODES * 4;         // 8000*64
constexpr size_t U_F2    = U_F1 + (size_t)NODES * 64;
constexpr size_t U_INT   = U_F2 + (size_t)NODES * 64;        // int region
constexpr size_t IOFF_CNT  = 0;
constexpr size_t IOFF_OFFS = 8192;
constexpr size_t IOFF_CUR  = 16384;
constexpr size_t IOFF_SSRC = 24576;

// ---------------- device helpers ----------------
typedef _Float16 h2_t __attribute__((ext_vector_type(2)));

#if __has_builtin(__builtin_amdgcn_fdot2)
__device__ __forceinline__ float fdot2u(uint32_t a, uint32_t b, float c) {
  return __builtin_amdgcn_fdot2(__builtin_bit_cast(h2_t, a), __builtin_bit_cast(h2_t, b), c, false);
}
#else
__device__ __forceinline__ float fdot2u(uint32_t a, uint32_t b, float c) {
  h2_t x = __builtin_bit_cast(h2_t, a), y = __builtin_bit_cast(h2_t, b);
  return fmaf((float)x[1], (float)y[1], fmaf((float)x[0], (float)y[0], c));
}
#endif
__device__ __forceinline__ uint32_t pk16(float a, float b) {
  return __builtin_bit_cast(uint32_t, __builtin_amdgcn_cvt_pkrtz(a, b));
}
__device__ __forceinline__ uint32_t rdlu(uint32_t v, int k) {
  return (uint32_t)__builtin_amdgcn_readlane((int)v, k);
}
__device__ __forceinline__ float sigf(float x) { return 1.f / (1.f + __expf(-x)); }
__device__ __forceinline__ float tanhfast(float x) { return 1.f - 2.f / (__expf(2.f * x) + 1.f); }

// ---------------- weight permute + f16 pack ----------------
// wph[kp][c], c = 4*j + q holds half2( W[g][2kp], W[g][2kp+1] ), g = q*64 + j.
__global__ void permute_pack(const float* __restrict__ Wih, const float* __restrict__ Whh,
                             const float* __restrict__ bias, uint32_t* __restrict__ wph,
                             float* __restrict__ bp, int DIN) {
  const int kp = blockIdx.x;
  const int c = threadIdx.x;
  const int j = c >> 2, q = c & 3;
  const int g = q * 64 + j;
  const int k0 = 2 * kp;
  float a, b;
  if (k0 < DIN) { a = Wih[g * DIN + k0]; b = Wih[g * DIN + k0 + 1]; }
  else { const int r = k0 - DIN; a = Whh[g * 64 + r]; b = Whh[g * 64 + r + 1]; }
  wph[kp * 256 + c] = pk16(a, b);
  if (kp == 0) bp[c] = bias[g];
}

// pack fp32 into half2 pairs
__global__ void pack_x(const float* __restrict__ x, uint32_t* __restrict__ out, int n) {
  const int i = blockIdx.x * 256 + threadIdx.x;
  if (i < n) out[i] = pk16(x[2 * i], x[2 * i + 1]);
}

// ---------------- LSTM scan (f16 dot2, all weights in LDS) ----------------
template<int DIN, bool WRITE_ALL, int M>
__global__ __launch_bounds__(512)
void lstm_scan(const uint32_t* __restrict__ xpk,
               const uint32_t* __restrict__ wpF, const uint32_t* __restrict__ wpB,
               const float* __restrict__ bpF, const float* __restrict__ bpB,
               float* __restrict__ lastout, uint32_t* __restrict__ hpkout) {
  constexpr int KPX = DIN / 2;           // input k-pairs
  constexpr int KP  = KPX + 32;          // + recurrent k-pairs
  __shared__ __align__(16) uint32_t wph[KP * 256];
  const int dir = blockIdx.y;
  const uint32_t* __restrict__ wp = dir ? wpB : wpF;
  const float* __restrict__ bp = dir ? bpB : bpF;
  for (int idx = threadIdx.x; idx < KP * 64; idx += 512)
    ((uint4*)wph)[idx] = ((const uint4*)wp)[idx];
  __syncthreads();

  const int wv = threadIdx.x >> 6;
  const int j  = threadIdx.x & 63;
  const int n0 = (blockIdx.x * 8 + wv) * M;
  const float4 bias4 = *(const float4*)(bp + 4 * j);

  float hreg[M], creg[M];
  uint32_t hpk[M];
#pragma unroll
  for (int m = 0; m < M; ++m) { hreg[m] = 0.f; creg[m] = 0.f; hpk[m] = 0u; }

  constexpr int XS = (DIN == 32) ? NN * 16 : 64;  // per-step stride in uints
  int xbase[M];
#pragma unroll
  for (int m = 0; m < M; ++m) {
    const int n = n0 + m;
    if (DIN == 32) {
      const int b = n / NN, node = n - b * NN;
      xbase[m] = (b * SEQ * NN + node) * 16 + (j & 15);
    } else {
      xbase[m] = (n * SEQ) * 64 + j;
    }
  }

  const bool rev = (dir != 0);
  const int steps = (!WRITE_ALL && rev) ? 1 : SEQ;
  const int sstep = rev ? -1 : 1;
  int s = rev ? SEQ - 1 : 0;

  uint32_t xu[M];
#pragma unroll
  for (int m = 0; m < M; ++m) xu[m] = xpk[xbase[m] + s * XS];

  for (int t = 0; t < steps; ++t, s += sstep) {
    uint32_t xun[M];
#pragma unroll
    for (int m = 0; m < M; ++m) xun[m] = xu[m];
    if (t + 1 < steps) {
#pragma unroll
      for (int m = 0; m < M; ++m) xun[m] = xpk[xbase[m] + (s + sstep) * XS];
    }

    float4 acc[M];
#pragma unroll
    for (int m = 0; m < M; ++m) acc[m] = bias4;

    // ---- input projection ----
#pragma unroll 2
    for (int kp = 0; kp < KPX; ++kp) {
      const uint4 w4 = *(const uint4*)&wph[kp * 256 + 4 * j];
#pragma unroll
      for (int m = 0; m < M; ++m) {
        const uint32_t b2 = rdlu(xu[m], kp);
        acc[m].x = fdot2u(w4.x, b2, acc[m].x);
        acc[m].y = fdot2u(w4.y, b2, acc[m].y);
        acc[m].z = fdot2u(w4.z, b2, acc[m].z);
        acc[m].w = fdot2u(w4.w, b2, acc[m].w);
      }
    }
    // ---- recurrent part ----
#pragma unroll 2
    for (int kh = 0; kh < 32; ++kh) {
      const uint4 w4 = *(const uint4*)&wph[(KPX + kh) * 256 + 4 * j];
#pragma unroll
      for (int m = 0; m < M; ++m) {
        const uint32_t b2 = rdlu(hpk[m], 2 * kh);
        acc[m].x = fdot2u(w4.x, b2, acc[m].x);
        acc[m].y = fdot2u(w4.y, b2, acc[m].y);
        acc[m].z = fdot2u(w4.z, b2, acc[m].z);
        acc[m].w = fdot2u(w4.w, b2, acc[m].w);
      }
    }

    // ---- gate nonlinearities + h pack ----
#pragma unroll
    for (int m = 0; m < M; ++m) {
      const float iv = sigf(acc[m].x);
      const float fv = sigf(acc[m].y);
      const float gv = tanhfast(acc[m].z);
      const float ov = sigf(acc[m].w);
      const float c = fv * creg[m] + iv * gv;
      const float h = ov * tanhfast(c);
      creg[m] = c; hreg[m] = h;
      const float hn = __shfl_down(h, 1);
      hpk[m] = pk16(h, hn);
      if (WRITE_ALL && (j & 1) == 0)
        hpkout[((size_t)(n0 + m) * SEQ + s) * 64 + dir * 32 + (j >> 1)] = hpk[m];
    }
#pragma unroll
    for (int m = 0; m < M; ++m) xu[m] = xun[m];
  }
  if (!WRITE_ALL) {
#pragma unroll
    for (int m = 0; m < M; ++m)
      lastout[(size_t)(n0 + m) * 128 + dir * 64 + j] = hreg[m];
  }
}

// ---------------- CSR build (once; shared by both GAT layers) ----------------
__global__ void csr_zero(int* cnt) {
  const int i = blockIdx.x * 256 + threadIdx.x;
  if (i < NODES + 1) cnt[i] = 0;
}
__global__ void csr_count(const int* __restrict__ ei, int* __restrict__ cnt) {
  const int e = blockIdx.x * 256 + threadIdx.x;
  if (e >= NEDGE) return;
  int dst;
  if (e < BB * EPB) { const int b = e / EPB, i = e - b * EPB; dst = ei[EPB + i] + b * NN; }
  else dst = e - BB * EPB;
  atomicAdd(&cnt[dst], 1);
}
__global__ void csr_scan(const int* __restrict__ cnt, int* __restrict__ offs, int* __restrict__ cur) {
  __shared__ int sums[1024];
  const int t = threadIdx.x;
  const int base = t * 8;
  int loc[8]; int s = 0;
#pragma unroll
  for (int i = 0; i < 8; ++i) {
    const int v = (base + i < NODES) ? cnt[base + i] : 0;
    loc[i] = s; s += v;
  }
  sums[t] = s; __syncthreads();
  for (int off = 1; off < 1024; off <<= 1) {
    int v = 0;
    if (t >= off) v = sums[t - off];
    __syncthreads();
    sums[t] += v;
    __syncthreads();
  }
  const int pre = (t == 0) ? 0 : sums[t - 1];
#pragma unroll
  for (int i = 0; i < 8; ++i) {
    if (base + i < NODES) { const int o = pre + loc[i]; offs[base + i] = o; cur[base + i] = o; }
  }
  if (t == 1023) offs[NODES] = sums[1023];
}
__global__ void csr_fill(const int* __restrict__ ei, int* __restrict__ cur, int* __restrict__ ssrc) {
  const int e = blockIdx.x * 256 + threadIdx.x;
  if (e >= NEDGE) return;
  int src, dst;
  if (e < BB * EPB) {
    const int b = e / EPB, i = e - b * EPB;
    src = ei[i] + b * NN; dst = ei[EPB + i] + b * NN;
  } else { src = dst = e - BB * EPB; }
  const int pos = atomicAdd(&cur[dst], 1);
  ssrc[pos] = src;
}

// ---------------- GAT: xp = feat @ gW, plus per-head attention dots ----------------
template<int F>
__global__ __launch_bounds__(256)
void gat_prep(const float* __restrict__ feat, const float* __restrict__ gW,
              const float* __restrict__ asrc, const float* __restrict__ adst,
              float* __restrict__ xp, float* __restrict__ as_, float* __restrict__ ad_) {
  __shared__ float xrow[8 * F];
  const int n0 = blockIdx.x * 8;
  for (int idx = threadIdx.x; idx < 8 * F; idx += 256) xrow[idx] = feat[(size_t)n0 * F + idx];
  __syncthreads();
  const int g = threadIdx.x;           // 0..255 ; head = g>>6 == wave id
  float acc[8];
#pragma unroll
  for (int m = 0; m < 8; ++m) acc[m] = 0.f;
  for (int d = 0; d < F; ++d) {
    const float w = gW[d * 256 + g];
#pragma unroll
    for (int m = 0; m < 8; ++m) acc[m] = fmaf(xrow[m * F + d], w, acc[m]);
  }
#pragma unroll
  for (int m = 0; m < 8; ++m) xp[(size_t)(n0 + m) * 256 + g] = acc[m];
  const float av = asrc[g], dv = adst[g];
  const int h = g >> 6;
#pragma unroll
  for (int m = 0; m < 8; ++m) {
    float s1 = acc[m] * av, s2 = acc[m] * dv;
#pragma unroll
    for (int off = 1; off < 64; off <<= 1) {
      s1 += __shfl_xor(s1, off);
      s2 += __shfl_xor(s2, off);
    }
    if ((g & 63) == 0) {
      as_[(n0 + m) * 4 + h] = s1;
      ad_[(n0 + m) * 4 + h] = s2;
    }
  }
}

// ---------------- GAT: per-destination-node softmax aggregation ----------------
__global__ __launch_bounds__(256)
void gat_agg(const int* __restrict__ offs, const int* __restrict__ ssrc,
             const float* __restrict__ as_, const float* __restrict__ ad_,
             const float* __restrict__ xp, const float* __restrict__ gbias,
             float* __restrict__ outf) {
  const int v = blockIdx.x * 4 + (threadIdx.x >> 6);
  const int lane = threadIdx.x & 63;
  const int beg = offs[v], end = offs[v + 1];
  const float4 adv = *(const float4*)(ad_ + v * 4);

  // pass 1: per-head segment max
  float m0 = -1e30f, m1 = -1e30f, m2 = -1e30f, m3 = -1e30f;
  for (int i = beg + lane; i < end; i += 64) {
    const int sn = ssrc[i];
    const float4 asv = *(const float4*)(as_ + sn * 4);
    float e;
    e = asv.x + adv.x; e = e > 0.f ? e : 0.2f * e; m0 = fmaxf(m0, e);
    e = asv.y + adv.y; e = e > 0.f ? e : 0.2f * e; m1 = fmaxf(m1, e);
    e = asv.z + adv.z; e = e > 0.f ? e : 0.2f * e; m2 = fmaxf(m2, e);
    e = asv.w + adv.w; e = e > 0.f ? e : 0.2f * e; m3 = fmaxf(m3, e);
  }
#pragma unroll
  for (int off = 1; off < 64; off <<= 1) {
    m0 = fmaxf(m0, __shfl_xor(m0, off));
    m1 = fmaxf(m1, __shfl_xor(m1, off));
    m2 = fmaxf(m2, __shfl_xor(m2, off));
    m3 = fmaxf(m3, __shfl_xor(m3, off));
  }

  // pass 2: weighted aggregation (lane = output channel c)
  float a0 = 0, a1 = 0, a2 = 0, a3 = 0, d0 = 0, d1 = 0, d2 = 0, d3 = 0;
  for (int i = beg; i < end; ++i) {
    const int sn = ssrc[i];
    const float4 asv = *(const float4*)(as_ + sn * 4);
    const float* xr = xp + (size_t)sn * 256;
    float e, w;
    e = asv.x + adv.x; e = e > 0.f ? e : 0.2f * e; w = __expf(e - m0); d0 += w; a0 = fmaf(w, xr[lane], a0);
    e = asv.y + adv.y; e = e > 0.f ? e : 0.2f * e; w = __expf(e - m1); d1 += w; a1 = fmaf(w, xr[64 + lane], a1);
    e = asv.z + adv.z; e = e > 0.f ? e : 0.2f * e; w = __expf(e - m2); d2 += w; a2 = fmaf(w, xr[128 + lane], a2);
    e = asv.w + adv.w; e = e > 0.f ? e : 0.2f * e; w = __expf(e - m3); d3 += w; a3 = fmaf(w, xr[192 + lane], a3);
  }
  const float r = 0.25f * (a0 / (d0 + 1e-16f) + a1 / (d1 + 1e-16f) +
                           a2 / (d2 + 1e-16f) + a3 / (d3 + 1e-16f)) + gbias[lane];
  outf[(size_t)v * 64 + lane] = fmaxf(r, 0.f);
}

// ---------------- final: node-mean per batch + 2-layer MLP ----------------
__global__ void final_mlp(const float* __restrict__ feat2,
                          const float* __restrict__ fW1, const float* __restrict__ fb1,
                          const float* __restrict__ fW2, const float* __restrict__ fb2,
                          float* __restrict__ out) {
  const int b = blockIdx.x;
  __shared__ float part[4][64];
  __shared__ float y[64];
  __shared__ float hh[32];
  const int t = threadIdx.x;
  const int c = t & 63, r = t >> 6;
  float s = 0.f;
  for (int i = r; i < NN; i += 4) s += feat2[(size_t)(b * NN + i) * 64 + c];
  part[r][c] = s; __syncthreads();
  if (t < 64) y[t] = (part[0][t] + part[1][t] + part[2][t] + part[3][t]) * (1.0f / NN);
  __syncthreads();
  if (t < 32) {
    float a = fb1[t];
    for (int cc = 0; cc < 64; ++cc) a = fmaf(y[cc], fW1[t * 64 + cc], a);
    hh[t] = fmaxf(a, 0.f);
  }
  __syncthreads();
  if (t == 0) {
    float o = fb2[0];
    for (int jj = 0; jj < 32; ++jj) o = fmaf(hh[jj], fW2[jj], o);
    out[b] = o;
  }
}

// ---------------- launch ----------------
extern "C" void kernel_launch(void* const* d_in, const int* in_sizes, int n_in,
                              void* d_out, int out_size, void* d_ws, size_t ws_size,
                              hipStream_t stream) {
  const float* x_seq = (const float*)d_in[0];
  const int*   ei    = (const int*)d_in[1];
  const float* Wih0f = (const float*)d_in[2];  const float* Whh0f = (const float*)d_in[3];  const float* b0f = (const float*)d_in[4];
  const float* Wih0b = (const float*)d_in[5];  const float* Whh0b = (const float*)d_in[6];  const float* b0b = (const float*)d_in[7];
  const float* Wih1f = (const float*)d_in[8];  const float* Whh1f = (const float*)d_in[9];  const float* b1f = (const float*)d_in[10];
  const float* Wih1b = (const float*)d_in[11]; const float* Whh1b = (const float*)d_in[12]; const float* b1b = (const float*)d_in[13];
  const float* gW0 = (const float*)d_in[14]; const float* gas0 = (const float*)d_in[15];
  const float* gad0 = (const float*)d_in[16]; const float* gb0 = (const float*)d_in[17];
  const float* gW1 = (const float*)d_in[18]; const float* gas1 = (const float*)d_in[19];
  const float* gad1 = (const float*)d_in[20]; const float* gb1 = (const float*)d_in[21];
  const float* fW1 = (const float*)d_in[22]; const float* fb1 = (const float*)d_in[23];
  const float* fW2 = (const float*)d_in[24]; const float* fb2 = (const float*)d_in[25];

  uint32_t* wsu = (uint32_t*)d_ws;
  float*    wsf = (float*)d_ws;
  uint32_t* wph0f = wsu + U_WPH0F; uint32_t* wph0b = wsu + U_WPH0B;
  uint32_t* wph1f = wsu + U_WPH1F; uint32_t* wph1b = wsu + U_WPH1B;
  float* bp0f = wsf + U_BP0F; float* bp0b = wsf + U_BP0B;
  float* bp1f = wsf + U_BP1F; float* bp1b = wsf + U_BP1B;
  uint32_t* xpk = wsu + U_XPK;
  uint32_t* h0p = wsu + U_H0P;
  float* last = wsf + U_LAST;
  float* xp   = wsf + U_XP;
  float* as_  = wsf + U_AS;  float* ad_ = wsf + U_AD;
  float* f1   = wsf + U_F1;  float* f2  = wsf + U_F2;
  int* iws  = (int*)(wsf + U_INT);
  int* cnt  = iws + IOFF_CNT;  int* offs = iws + IOFF_OFFS;
  int* cur  = iws + IOFF_CUR;  int* ssrc = iws + IOFF_SSRC;

  // weight permute+pack (tiny)
  permute_pack<<<48, 256, 0, stream>>>(Wih0f, Whh0f, b0f, wph0f, bp0f, 32);
  permute_pack<<<48, 256, 0, stream>>>(Wih0b, Whh0b, b0b, wph0b, bp0b, 32);
  permute_pack<<<96, 256, 0, stream>>>(Wih1f, Whh1f, b1f, wph1f, bp1f, 128);
  permute_pack<<<96, 256, 0, stream>>>(Wih1b, Whh1b, b1b, wph1b, bp1b, 128);
  pack_x<<<(NODES * SEQ * 16 + 255) / 256, 256, 0, stream>>>(x_seq, xpk, NODES * SEQ * 16);

  // LSTM layer 0 (both dirs, packed h0 out), layer 1 (fwd full + bwd 1 step -> last fp32)
  lstm_scan<32, true, 4><<<dim3(250, 2), 512, 0, stream>>>(xpk, wph0f, wph0b, bp0f, bp0b, nullptr, h0p);
  lstm_scan<128, false, 4><<<dim3(250, 2), 512, 0, stream>>>(h0p, wph1f, wph1b, bp1f, bp1b, last, nullptr);

  // CSR of the (fixed) graph
  csr_zero<<<32, 256, 0, stream>>>(cnt);
  csr_count<<<(NEDGE + 255) / 256, 256, 0, stream>>>(ei, cnt);
  csr_scan<<<1, 1024, 0, stream>>>(cnt, offs, cur);
  csr_fill<<<(NEDGE + 255) / 256, 256, 0, stream>>>(ei, cur, ssrc);

  // GAT layer 0 (input: last, F=128)
  gat_prep<128><<<1000, 256, 0, stream>>>(last, gW0, gas0, gad0, xp, as_, ad_);
  gat_agg<<<2000, 256, 0, stream>>>(offs, ssrc, as_, ad_, xp, gb0, f1);
  // GAT layer 1 (input: f1, F=64)
  gat_prep<64><<<1000, 256, 0, stream>>>(f1, gW1, gas1, gad1, xp, as_, ad_);
  gat_agg<<<2000, 256, 0, stream>>>(offs, ssrc, as_, ad_, xp, gb1, f2);

  // mean over nodes + MLP head
  final_mlp<<<4, 256, 0, stream>>>(f2, fW1, fb1, fW2, fb2, (float*)d_out);
}